// Round 16
// baseline (190.096 us; speedup 1.0000x reference)
//
#include <hip/hip_runtime.h>
#include <hip/hip_bf16.h>

// Problem constants: B=2, T=2048, C=1024, H=16, D=64
#define BSZ 2
#define SEQ 2048
#define CDIM 1024
#define NHEAD 16
#define HDIM 64
#define M_GEMM (BSZ * SEQ)      // 4096
#define N_GEMM (3 * CDIM)       // 3072
#define K_GEMM CDIM             // 1024
#define QK_PITCH (2 * CDIM)     // 2048: qk buffer row pitch (Q|K only)

typedef __attribute__((ext_vector_type(8))) short short8;   // 8 bf16 = 16B
typedef __attribute__((ext_vector_type(4))) short short4v;  // 8B
typedef __attribute__((ext_vector_type(4))) float f32x4;

__device__ __forceinline__ short bf16_rn(float f) {
    unsigned u = __builtin_bit_cast(unsigned, f);
    u += 0x7FFF + ((u >> 16) & 1);          // round-to-nearest-even
    return (short)(u >> 16);
}

// async 16B global -> LDS (wave-uniform LDS base; HW adds lane*16)
__device__ __forceinline__ void gl2lds16(const short* g, short* l) {
    __builtin_amdgcn_global_load_lds(
        (const __attribute__((address_space(1))) unsigned int*)g,
        (__attribute__((address_space(3))) unsigned int*)l, 16, 0, 0);
}

// ------------- Kernel 0: fused fp32->bf16 conversions ------------------------
// blocks [0, 2048): x -> xb (same layout). blocks [2048, 2816): W -> W^T tiles.
__global__ __launch_bounds__(256) void cvt_fused(const float* __restrict__ X,
                                                 const float* __restrict__ W,
                                                 short* __restrict__ Xb,
                                                 short* __restrict__ WT) {
    const int tid = threadIdx.x;
    if (blockIdx.x < 2048) {
        size_t idx = ((size_t)blockIdx.x * 256 + tid) * 8;
        float4 a = *(const float4*)&X[idx];
        float4 b = *(const float4*)&X[idx + 4];
        short8 o;
        o[0] = bf16_rn(a.x); o[1] = bf16_rn(a.y); o[2] = bf16_rn(a.z); o[3] = bf16_rn(a.w);
        o[4] = bf16_rn(b.x); o[5] = bf16_rn(b.y); o[6] = bf16_rn(b.z); o[7] = bf16_rn(b.w);
        *(short8*)&Xb[idx] = o;
        return;
    }
    __shared__ short T[64][72];
    const int bid = blockIdx.x - 2048;          // 0..767
    const int n0 = (bid % 48) * 64;
    const int k0 = (bid / 48) * 64;
#pragma unroll
    for (int pass = 0; pass < 4; ++pass) {
        int i = pass * 256 + tid;
        int kr = i >> 4;
        int n4 = i & 15;
        float4 v = *(const float4*)&W[(size_t)(k0 + kr) * N_GEMM + n0 + n4 * 4];
        T[n4 * 4 + 0][kr] = bf16_rn(v.x);
        T[n4 * 4 + 1][kr] = bf16_rn(v.y);
        T[n4 * 4 + 2][kr] = bf16_rn(v.z);
        T[n4 * 4 + 3][kr] = bf16_rn(v.w);
    }
    __syncthreads();
#pragma unroll
    for (int pass = 0; pass < 2; ++pass) {
        int o = pass * 256 + tid;
        int nr = o >> 3;
        int c8 = o & 7;
        *(short8*)&WT[(size_t)(n0 + nr) * K_GEMM + k0 + c8 * 8] =
            *(const short8*)&T[nr][c8 * 8];
    }
}

// -------- Kernel 1: qkv = x @ W + b, bf16 MFMA 16x16x32, BK=32 DBUF ----------
// 128x128 tile, 32 K-iters, ONE barrier per iter: stage(kt+1, buf^1) issued
// before compute(kt, buf), barrier drains prefetch + guards reuse (the R11->R14
// attention pattern; the old BK=64 loop paid 2 exposed barrier drains/iter).
// XOR-4 chunk swizzle (R4-verified): slot s of row r holds chunk s^(r&3).
// Q cols pre-scaled by 0.125*log2(e) so attention uses exp2 directly.
#define GBK 32

__global__ __launch_bounds__(256) void qkv_gemm_mfma(const short* __restrict__ A,
                                                     const short* __restrict__ Bt,
                                                     const float* __restrict__ bias,
                                                     short* __restrict__ Yqk,
                                                     short* __restrict__ Yv) {
    __shared__ short Asl[2][128 * GBK];  // 2 x 8 KB
    __shared__ short Bsl[2][128 * GBK];  // 2 x 8 KB

    const int tid = threadIdx.x;
    const int w = tid >> 6;
    const int l16 = tid & 15;
    const int quad = (tid & 63) >> 4;
    const int wm = w >> 1, wn = w & 1;
    const int m0 = blockIdx.y * 128;
    const int n0 = blockIdx.x * 128;

    f32x4 acc[4][4];
#pragma unroll
    for (int i = 0; i < 4; ++i)
#pragma unroll
        for (int j = 0; j < 4; ++j) acc[i][j] = (f32x4){0.f, 0.f, 0.f, 0.f};

    // staging: 2 issues per matrix per buffer; chunk cid = p*256 + tid
    // row = cid>>2 (4 chunks/row), slot = cid&3, global chunk = slot^(row&3)
    int arow[2], gofs[2], ldso[2];
#pragma unroll
    for (int p = 0; p < 2; ++p) {
        int cid = p * 256 + tid;
        arow[p] = cid >> 2;
        gofs[p] = ((cid & 3) ^ (arow[p] & 3)) * 8;
        ldso[p] = (p * 256 + w * 64) * 8;    // wave-uniform chunk base (shorts)
    }
    const int fsw = quad ^ (l16 & 3);        // frag-read swizzle slot

    // prologue: stage kt=0 into buf 0
#pragma unroll
    for (int p = 0; p < 2; ++p) {
        gl2lds16(A + (size_t)(m0 + arow[p]) * K_GEMM + gofs[p], &Asl[0][ldso[p]]);
        gl2lds16(Bt + (size_t)(n0 + arow[p]) * K_GEMM + gofs[p], &Bsl[0][ldso[p]]);
    }
    __syncthreads();

    for (int kt = 0; kt < K_GEMM; kt += GBK) {
        const int cur = (kt >> 5) & 1;

        // prefetch next K-slab into the other buffer (overlaps the MFMAs)
        if (kt + GBK < K_GEMM) {
#pragma unroll
            for (int p = 0; p < 2; ++p) {
                gl2lds16(A + (size_t)(m0 + arow[p]) * K_GEMM + kt + GBK + gofs[p],
                         &Asl[cur ^ 1][ldso[p]]);
                gl2lds16(Bt + (size_t)(n0 + arow[p]) * K_GEMM + kt + GBK + gofs[p],
                         &Bsl[cur ^ 1][ldso[p]]);
            }
        }

        short8 af[4], bfr[4];
#pragma unroll
        for (int i = 0; i < 4; ++i) {
            int ra = wm * 64 + i * 16 + l16;
            int rb = wn * 64 + i * 16 + l16;
            af[i] = *(const short8*)&Asl[cur][(ra * 4 + fsw) * 8];
            bfr[i] = *(const short8*)&Bsl[cur][(rb * 4 + fsw) * 8];
        }
#pragma unroll
        for (int i = 0; i < 4; ++i)
#pragma unroll
            for (int j = 0; j < 4; ++j)
                acc[i][j] = __builtin_amdgcn_mfma_f32_16x16x32_bf16(
                    af[i], bfr[j], acc[i][j], 0, 0, 0);

        // one barrier/iter: drains prefetch + guards buffer reuse
        __syncthreads();
    }

    if (n0 >= 2 * CDIM) {
        // V block: write transposed, 4 consecutive rows packed per 8B store
#pragma unroll
        for (int i = 0; i < 4; ++i) {
            int row0 = m0 + wm * 64 + i * 16 + quad * 4;
#pragma unroll
            for (int j = 0; j < 4; ++j) {
                int colg = n0 + wn * 64 + j * 16 + l16;
                float bb = bias[colg];
                short4v pk;
#pragma unroll
                for (int r = 0; r < 4; ++r) pk[r] = bf16_rn(acc[i][j][r] + bb);
                *(short4v*)&Yv[(size_t)(colg - 2 * CDIM) * M_GEMM + row0] = pk;
            }
        }
    } else {
        // Q pre-scale folds BOTH 1/sqrt(64) and log2(e): attn does p = 2^s
        const float qs = (n0 < CDIM) ? 0.125f * 1.44269504f : 1.0f;
#pragma unroll
        for (int i = 0; i < 4; ++i)
#pragma unroll
            for (int r = 0; r < 4; ++r) {
                int row = m0 + wm * 64 + i * 16 + quad * 4 + r;
#pragma unroll
                for (int j = 0; j < 4; ++j) {
                    int colg = n0 + wn * 64 + j * 16 + l16;
                    Yqk[(size_t)row * QK_PITCH + colg] =
                        bf16_rn((acc[i][j][r] + bias[colg]) * qs);
                }
            }
    }
}

// ---------- Kernel 2: causal flash attention, scrambled-qt coset balance -----
// R14 winner unchanged except softmax uses exp2f (Q carries 0.125*log2e).
// 64 q-rows, 4 waves x 16; dbuf K/V, one barrier/tile; no-max softmax; XOR
// swizzle (conflict-free); wave-private Ps; coset-balanced qt mapping
// (constant 66 tile-iters per CU under round-robin block->CU; bijective per
// band so correctness is mapping-independent).
__global__ __launch_bounds__(256) void attn_mfma(const short* __restrict__ qk,
                                                 const short* __restrict__ vT,
                                                 float* __restrict__ out) {
    const int b = blockIdx.z;
    const int h = blockIdx.y;
    const int bx = blockIdx.x;           // 0..31
    const int u = h + 16 * b;            // 0..31
    const int band = u >> 3;             // 0..3
    const int base = (band & 2) ? ((bx + 16) & 31) : bx;
    const int qt = (band & 1) ? (31 - base) : base;
    const int tid = threadIdx.x;
    const int w = tid >> 6;
    const int lane = tid & 63;
    const int quad = lane >> 4;
    const int l16 = lane & 15;
    const int q0 = qt * 64;

    __shared__ short Ks[2][64 * 64];     // [buf][key][d], chunk-swizzled 16 KB
    __shared__ short Vt[2][64 * 64];     // [buf][d][key], chunk-swizzled 16 KB
    __shared__ short Ps[4 * 16 * 64];    // per-wave [q][key]              8 KB

    // staging descriptors: issue p covers chunks cid = p*256 + w*64 + lane
    int koff[2], voff[2], ldso[2];
#pragma unroll
    for (int p = 0; p < 2; ++p) {
        int cid = p * 256 + w * 64 + lane;
        int row = cid >> 3;
        int c = (cid & 7) ^ (row & 7);
        koff[p] = row * QK_PITCH + c * 8;
        voff[p] = row * M_GEMM + c * 8;
        ldso[p] = (p * 256 + w * 64) * 8;    // wave-uniform chunk base (shorts)
    }

    // Q fragments (A-layout: A[m=l16][k=quad*8+j])
    const short* qrow = qk + (size_t)(b * SEQ + q0 + w * 16 + l16) * QK_PITCH + h * HDIM;
    short8 aq[2];
    aq[0] = *(const short8*)(qrow + quad * 8);
    aq[1] = *(const short8*)(qrow + 32 + quad * 8);

    float l_run[4] = {0.f, 0.f, 0.f, 0.f};
    f32x4 o_acc[4];
#pragma unroll
    for (int dt = 0; dt < 4; ++dt) o_acc[dt] = (f32x4){0.f, 0.f, 0.f, 0.f};

    const int rowg0 = q0 + w * 16 + quad * 4;
    const short* kb0 = qk + (size_t)(b * SEQ) * QK_PITCH + CDIM + h * HDIM;
    const short* vb0 = vT + (size_t)(h * HDIM) * M_GEMM + b * SEQ;

    const int ksl = l16 & 7;
    short* PsW = &Ps[w * 1024];

    // prologue: stage tile 0 into buf 0
#pragma unroll
    for (int p = 0; p < 2; ++p) {
        gl2lds16(kb0 + koff[p], &Ks[0][ldso[p]]);
        gl2lds16(vb0 + voff[p], &Vt[0][ldso[p]]);
    }
    __syncthreads();                     // prologue staging drained

    for (int kt = 0; kt <= qt; ++kt) {
        const int cur = kt & 1;

        // prefetch tile kt+1 into the other buffer (overlaps compute)
        if (kt < qt) {
            const short* kbase = kb0 + (size_t)(kt + 1) * 64 * QK_PITCH;
            const short* vbase = vb0 + (kt + 1) * 64;
#pragma unroll
            for (int p = 0; p < 2; ++p) {
                gl2lds16(kbase + koff[p], &Ks[cur ^ 1][ldso[p]]);
                gl2lds16(vbase + voff[p], &Vt[cur ^ 1][ldso[p]]);
            }
        }

        const short* KsC = Ks[cur];
        const short* VtC = Vt[cur];

        // ---- QK^T: S[16 q][64 keys] (s already includes log2e factor) ----
        f32x4 s[4];
#pragma unroll
        for (int nt = 0; nt < 4; ++nt) s[nt] = (f32x4){0.f, 0.f, 0.f, 0.f};
#pragma unroll
        for (int nt = 0; nt < 4; ++nt)
#pragma unroll
            for (int ks = 0; ks < 2; ++ks) {
                short8 bk = *(const short8*)&KsC[(nt * 16 + l16) * 64 +
                                                 ((ks * 4 + quad) ^ ksl) * 8];
                s[nt] = __builtin_amdgcn_mfma_f32_16x16x32_bf16(aq[ks], bk, s[nt], 0, 0, 0);
            }

        // ---- no-max softmax: p = 2^s (native v_exp_f32); lane-local l ----
        if (kt < qt) {                   // full tile, wave-uniform
#pragma unroll
            for (int r = 0; r < 4; ++r) {
                const int qr = quad * 4 + r;
                float lsum = 0.f;
#pragma unroll
                for (int nt = 0; nt < 4; ++nt) {
                    float pp = exp2f(s[nt][r]);
                    lsum += pp;
                    int slot = (nt * 2 + (l16 >> 3)) ^ (qr & 7);
                    PsW[qr * 64 + slot * 8 + (l16 & 7)] = bf16_rn(pp);
                }
                l_run[r] += lsum;
            }
        } else {                         // diagonal tile: causal mask
            const int keyb = kt * 64 + l16;
#pragma unroll
            for (int r = 0; r < 4; ++r) {
                const int qr = quad * 4 + r;
                const int rowg = rowg0 + r;
                float lsum = 0.f;
#pragma unroll
                for (int nt = 0; nt < 4; ++nt) {
                    float pp = exp2f(s[nt][r]);
                    pp = ((keyb + nt * 16) > rowg) ? 0.f : pp;
                    lsum += pp;
                    int slot = (nt * 2 + (l16 >> 3)) ^ (qr & 7);
                    PsW[qr * 64 + slot * 8 + (l16 & 7)] = bf16_rn(pp);
                }
                l_run[r] += lsum;
            }
        }

        // ---- PV: O[16 q][64 d] += P @ V (Ps wave-private; no barrier) ----
#pragma unroll
        for (int dt = 0; dt < 4; ++dt)
#pragma unroll
            for (int ks = 0; ks < 2; ++ks) {
                short8 ap = *(const short8*)&PsW[l16 * 64 + ((ks * 4 + quad) ^ ksl) * 8];
                short8 bv = *(const short8*)&VtC[(dt * 16 + l16) * 64 +
                                                 ((ks * 4 + quad) ^ ksl) * 8];
                o_acc[dt] = __builtin_amdgcn_mfma_f32_16x16x32_bf16(ap, bv, o_acc[dt], 0, 0, 0);
            }

        // one barrier/tile: drains prefetch + guards buffer reuse
        __syncthreads();
    }

    // ---- epilogue: reduce l across the 16 key-lanes, normalize, store ----
#pragma unroll
    for (int r = 0; r < 4; ++r) {
        float l = l_run[r];
#pragma unroll
        for (int off = 1; off < 16; off <<= 1)
            l += __shfl_xor(l, off);
        float inv = 1.f / l;
        int row = q0 + w * 16 + quad * 4 + r;
        float* optr = out + (size_t)(b * SEQ + row) * CDIM + h * HDIM;
#pragma unroll
        for (int dt = 0; dt < 4; ++dt)
            optr[dt * 16 + l16] = o_acc[dt][r] * inv;
    }
}

// ------------------------------- launch --------------------------------------
extern "C" void kernel_launch(void* const* d_in, const int* in_sizes, int n_in,
                              void* d_out, int out_size, void* d_ws, size_t ws_size,
                              hipStream_t stream) {
    const float* x      = (const float*)d_in[0];   // [B,T,C] fp32
    const float* w_attn = (const float*)d_in[1];   // [C,3C]  fp32
    const float* b_attn = (const float*)d_in[2];   // [3C]    fp32
    float* out = (float*)d_out;                    // [B,T,C] fp32

    // workspace: qk [4096][2048] 16.78MB | vT [1024][4096] 8.39MB | xb 8.39MB | wT 6.29MB
    short* qk  = (short*)d_ws;
    short* vT  = (short*)((char*)d_ws + 16777216);
    short* xb  = (short*)((char*)d_ws + 25165824);
    short* wT  = (short*)((char*)d_ws + 33554432);

    cvt_fused<<<2048 + 768, 256, 0, stream>>>(x, w_attn, xb, wT);

    dim3 g1(N_GEMM / 128, M_GEMM / 128);                                // (24,32)
    qkv_gemm_mfma<<<g1, 256, 0, stream>>>(xb, wT, b_attn, qk, vT);

    dim3 g2(SEQ / 64, NHEAD, BSZ);                                      // (32,16,2)
    attn_mfma<<<g2, 256, 0, stream>>>(qk, vT, out);
}

// Round 17
// 167.460 us; speedup vs baseline: 1.1352x; 1.1352x over previous
//
#include <hip/hip_runtime.h>
#include <hip/hip_bf16.h>

// Problem constants: B=2, T=2048, C=1024, H=16, D=64
#define BSZ 2
#define SEQ 2048
#define CDIM 1024
#define NHEAD 16
#define HDIM 64
#define M_GEMM (BSZ * SEQ)      // 4096
#define N_GEMM (3 * CDIM)       // 3072
#define K_GEMM CDIM             // 1024
#define QK_PITCH (2 * CDIM)     // 2048: qk buffer row pitch (Q|K only)

typedef __attribute__((ext_vector_type(8))) short short8;   // 8 bf16 = 16B
typedef __attribute__((ext_vector_type(4))) short short4v;  // 8B
typedef __attribute__((ext_vector_type(4))) float f32x4;

__device__ __forceinline__ short bf16_rn(float f) {
    unsigned u = __builtin_bit_cast(unsigned, f);
    u += 0x7FFF + ((u >> 16) & 1);          // round-to-nearest-even
    return (short)(u >> 16);
}

// async 16B global -> LDS (wave-uniform LDS base; HW adds lane*16)
__device__ __forceinline__ void gl2lds16(const short* g, short* l) {
    __builtin_amdgcn_global_load_lds(
        (const __attribute__((address_space(1))) unsigned int*)g,
        (__attribute__((address_space(3))) unsigned int*)l, 16, 0, 0);
}

// ------------- Kernel 0: fused fp32->bf16 conversions ------------------------
// blocks [0, 2048): x -> xb (same layout). blocks [2048, 2816): W -> W^T tiles.
__global__ __launch_bounds__(256) void cvt_fused(const float* __restrict__ X,
                                                 const float* __restrict__ W,
                                                 short* __restrict__ Xb,
                                                 short* __restrict__ WT) {
    const int tid = threadIdx.x;
    if (blockIdx.x < 2048) {
        size_t idx = ((size_t)blockIdx.x * 256 + tid) * 8;
        float4 a = *(const float4*)&X[idx];
        float4 b = *(const float4*)&X[idx + 4];
        short8 o;
        o[0] = bf16_rn(a.x); o[1] = bf16_rn(a.y); o[2] = bf16_rn(a.z); o[3] = bf16_rn(a.w);
        o[4] = bf16_rn(b.x); o[5] = bf16_rn(b.y); o[6] = bf16_rn(b.z); o[7] = bf16_rn(b.w);
        *(short8*)&Xb[idx] = o;
        return;
    }
    __shared__ short T[64][72];
    const int bid = blockIdx.x - 2048;          // 0..767
    const int n0 = (bid % 48) * 64;
    const int k0 = (bid / 48) * 64;
#pragma unroll
    for (int pass = 0; pass < 4; ++pass) {
        int i = pass * 256 + tid;
        int kr = i >> 4;
        int n4 = i & 15;
        float4 v = *(const float4*)&W[(size_t)(k0 + kr) * N_GEMM + n0 + n4 * 4];
        T[n4 * 4 + 0][kr] = bf16_rn(v.x);
        T[n4 * 4 + 1][kr] = bf16_rn(v.y);
        T[n4 * 4 + 2][kr] = bf16_rn(v.z);
        T[n4 * 4 + 3][kr] = bf16_rn(v.w);
    }
    __syncthreads();
#pragma unroll
    for (int pass = 0; pass < 2; ++pass) {
        int o = pass * 256 + tid;
        int nr = o >> 3;
        int c8 = o & 7;
        *(short8*)&WT[(size_t)(n0 + nr) * K_GEMM + k0 + c8 * 8] =
            *(const short8*)&T[nr][c8 * 8];
    }
}

// -------- Kernel 1: qkv = x @ W + b, bf16 MFMA 16x16x32, BK=64 ---------------
// R14 measured-best form (R15's BK=32 dbuf regressed ~6us -> reverted).
// 128x128 tile, 16 K-iters, 32 MFMA/wave per barrier. XOR-8 chunk swizzle:
// LDS slot s of row r holds global chunk s^(r&7). Chunk = 16 B = 8 shorts.
// Q cols pre-scaled by 0.125*log2(e) so attention uses raw v_exp_f32 (2^s).
#define GBK 64

__global__ __launch_bounds__(256) void qkv_gemm_mfma(const short* __restrict__ A,
                                                     const short* __restrict__ Bt,
                                                     const float* __restrict__ bias,
                                                     short* __restrict__ Yqk,
                                                     short* __restrict__ Yv) {
    __shared__ short Asl[128 * GBK];     // 16 KB, 1024 chunks
    __shared__ short Bsl[128 * GBK];     // 16 KB

    const int tid = threadIdx.x;
    const int w = tid >> 6;
    const int l16 = tid & 15;
    const int quad = (tid & 63) >> 4;
    const int wm = w >> 1, wn = w & 1;
    const int m0 = blockIdx.y * 128;
    const int n0 = blockIdx.x * 128;

    f32x4 acc[4][4];
#pragma unroll
    for (int i = 0; i < 4; ++i)
#pragma unroll
        for (int j = 0; j < 4; ++j) acc[i][j] = (f32x4){0.f, 0.f, 0.f, 0.f};

    int arow[4], gofs[4];
#pragma unroll
    for (int p = 0; p < 4; ++p) {
        int cid = p * 256 + tid;
        arow[p] = cid >> 3;
        gofs[p] = ((cid & 7) ^ (arow[p] & 7)) * 8;
    }
    const int fsw = l16 & 7;             // frag-read swizzle (row&7 == l16&7)

    for (int kt = 0; kt < K_GEMM; kt += GBK) {
        __syncthreads();
#pragma unroll
        for (int p = 0; p < 4; ++p) {
            gl2lds16(A + (size_t)(m0 + arow[p]) * K_GEMM + kt + gofs[p],
                     &Asl[(p * 256 + w * 64) * 8]);   // chunk base *8 shorts
            gl2lds16(Bt + (size_t)(n0 + arow[p]) * K_GEMM + kt + gofs[p],
                     &Bsl[(p * 256 + w * 64) * 8]);
        }
        __syncthreads();

        short8 af[4][2], bfr[4][2];
#pragma unroll
        for (int i = 0; i < 4; ++i) {
            int ra = wm * 64 + i * 16 + l16;
            int rb = wn * 64 + i * 16 + l16;
#pragma unroll
            for (int ks = 0; ks < 2; ++ks) {
                af[i][ks] = *(const short8*)&Asl[(ra * 8 + ((ks * 4 + quad) ^ fsw)) * 8];
                bfr[i][ks] = *(const short8*)&Bsl[(rb * 8 + ((ks * 4 + quad) ^ fsw)) * 8];
            }
        }
#pragma unroll
        for (int i = 0; i < 4; ++i)
#pragma unroll
            for (int j = 0; j < 4; ++j)
#pragma unroll
                for (int ks = 0; ks < 2; ++ks)
                    acc[i][j] = __builtin_amdgcn_mfma_f32_16x16x32_bf16(
                        af[i][ks], bfr[j][ks], acc[i][j], 0, 0, 0);
    }

    if (n0 >= 2 * CDIM) {
        // V block: write transposed, 4 consecutive rows packed per 8B store
#pragma unroll
        for (int i = 0; i < 4; ++i) {
            int row0 = m0 + wm * 64 + i * 16 + quad * 4;
#pragma unroll
            for (int j = 0; j < 4; ++j) {
                int colg = n0 + wn * 64 + j * 16 + l16;
                float bb = bias[colg];
                short4v pk;
#pragma unroll
                for (int r = 0; r < 4; ++r) pk[r] = bf16_rn(acc[i][j][r] + bb);
                *(short4v*)&Yv[(size_t)(colg - 2 * CDIM) * M_GEMM + row0] = pk;
            }
        }
    } else {
        // Q pre-scale folds BOTH 1/sqrt(64) and log2(e): attn does p = 2^s
        const float qs = (n0 < CDIM) ? 0.125f * 1.44269504f : 1.0f;
#pragma unroll
        for (int i = 0; i < 4; ++i)
#pragma unroll
            for (int r = 0; r < 4; ++r) {
                int row = m0 + wm * 64 + i * 16 + quad * 4 + r;
#pragma unroll
                for (int j = 0; j < 4; ++j) {
                    int colg = n0 + wn * 64 + j * 16 + l16;
                    Yqk[(size_t)row * QK_PITCH + colg] =
                        bf16_rn((acc[i][j][r] + bias[colg]) * qs);
                }
            }
    }
}

// ---------- Kernel 2: causal flash attention, scrambled-qt coset balance -----
// R14 winner; softmax uses RAW v_exp_f32 via __builtin_amdgcn_exp2f (R15's
// exp2f lowered to libm __ocml_exp2_f32: +12 VGPR, +VALU -> 50->65us
// regression). Q carries 0.125*log2e from the GEMM. 64 q-rows, 4 waves x 16;
// dbuf K/V, one barrier/tile; no-max softmax; XOR swizzle; wave-private Ps;
// coset-balanced qt mapping (constant 66 tile-iters/CU, bijective per band).
__global__ __launch_bounds__(256) void attn_mfma(const short* __restrict__ qk,
                                                 const short* __restrict__ vT,
                                                 float* __restrict__ out) {
    const int b = blockIdx.z;
    const int h = blockIdx.y;
    const int bx = blockIdx.x;           // 0..31
    const int u = h + 16 * b;            // 0..31
    const int band = u >> 3;             // 0..3
    const int base = (band & 2) ? ((bx + 16) & 31) : bx;
    const int qt = (band & 1) ? (31 - base) : base;
    const int tid = threadIdx.x;
    const int w = tid >> 6;
    const int lane = tid & 63;
    const int quad = lane >> 4;
    const int l16 = lane & 15;
    const int q0 = qt * 64;

    __shared__ short Ks[2][64 * 64];     // [buf][key][d], chunk-swizzled 16 KB
    __shared__ short Vt[2][64 * 64];     // [buf][d][key], chunk-swizzled 16 KB
    __shared__ short Ps[4 * 16 * 64];    // per-wave [q][key]              8 KB

    // staging descriptors: issue p covers chunks cid = p*256 + w*64 + lane
    int koff[2], voff[2], ldso[2];
#pragma unroll
    for (int p = 0; p < 2; ++p) {
        int cid = p * 256 + w * 64 + lane;
        int row = cid >> 3;
        int c = (cid & 7) ^ (row & 7);
        koff[p] = row * QK_PITCH + c * 8;
        voff[p] = row * M_GEMM + c * 8;
        ldso[p] = (p * 256 + w * 64) * 8;    // wave-uniform chunk base (shorts)
    }

    // Q fragments (A-layout: A[m=l16][k=quad*8+j])
    const short* qrow = qk + (size_t)(b * SEQ + q0 + w * 16 + l16) * QK_PITCH + h * HDIM;
    short8 aq[2];
    aq[0] = *(const short8*)(qrow + quad * 8);
    aq[1] = *(const short8*)(qrow + 32 + quad * 8);

    float l_run[4] = {0.f, 0.f, 0.f, 0.f};
    f32x4 o_acc[4];
#pragma unroll
    for (int dt = 0; dt < 4; ++dt) o_acc[dt] = (f32x4){0.f, 0.f, 0.f, 0.f};

    const int rowg0 = q0 + w * 16 + quad * 4;
    const short* kb0 = qk + (size_t)(b * SEQ) * QK_PITCH + CDIM + h * HDIM;
    const short* vb0 = vT + (size_t)(h * HDIM) * M_GEMM + b * SEQ;

    const int ksl = l16 & 7;
    short* PsW = &Ps[w * 1024];

    // prologue: stage tile 0 into buf 0
#pragma unroll
    for (int p = 0; p < 2; ++p) {
        gl2lds16(kb0 + koff[p], &Ks[0][ldso[p]]);
        gl2lds16(vb0 + voff[p], &Vt[0][ldso[p]]);
    }
    __syncthreads();                     // prologue staging drained

    for (int kt = 0; kt <= qt; ++kt) {
        const int cur = kt & 1;

        // prefetch tile kt+1 into the other buffer (overlaps compute)
        if (kt < qt) {
            const short* kbase = kb0 + (size_t)(kt + 1) * 64 * QK_PITCH;
            const short* vbase = vb0 + (kt + 1) * 64;
#pragma unroll
            for (int p = 0; p < 2; ++p) {
                gl2lds16(kbase + koff[p], &Ks[cur ^ 1][ldso[p]]);
                gl2lds16(vbase + voff[p], &Vt[cur ^ 1][ldso[p]]);
            }
        }

        const short* KsC = Ks[cur];
        const short* VtC = Vt[cur];

        // ---- QK^T: S[16 q][64 keys] (s already includes log2e factor) ----
        f32x4 s[4];
#pragma unroll
        for (int nt = 0; nt < 4; ++nt) s[nt] = (f32x4){0.f, 0.f, 0.f, 0.f};
#pragma unroll
        for (int nt = 0; nt < 4; ++nt)
#pragma unroll
            for (int ks = 0; ks < 2; ++ks) {
                short8 bk = *(const short8*)&KsC[(nt * 16 + l16) * 64 +
                                                 ((ks * 4 + quad) ^ ksl) * 8];
                s[nt] = __builtin_amdgcn_mfma_f32_16x16x32_bf16(aq[ks], bk, s[nt], 0, 0, 0);
            }

        // ---- no-max softmax: p = 2^s, ONE v_exp_f32 each; lane-local l ----
        if (kt < qt) {                   // full tile, wave-uniform
#pragma unroll
            for (int r = 0; r < 4; ++r) {
                const int qr = quad * 4 + r;
                float lsum = 0.f;
#pragma unroll
                for (int nt = 0; nt < 4; ++nt) {
                    float pp = __builtin_amdgcn_exp2f(s[nt][r]);
                    lsum += pp;
                    int slot = (nt * 2 + (l16 >> 3)) ^ (qr & 7);
                    PsW[qr * 64 + slot * 8 + (l16 & 7)] = bf16_rn(pp);
                }
                l_run[r] += lsum;
            }
        } else {                         // diagonal tile: causal mask
            const int keyb = kt * 64 + l16;
#pragma unroll
            for (int r = 0; r < 4; ++r) {
                const int qr = quad * 4 + r;
                const int rowg = rowg0 + r;
                float lsum = 0.f;
#pragma unroll
                for (int nt = 0; nt < 4; ++nt) {
                    float pp = __builtin_amdgcn_exp2f(s[nt][r]);
                    pp = ((keyb + nt * 16) > rowg) ? 0.f : pp;
                    lsum += pp;
                    int slot = (nt * 2 + (l16 >> 3)) ^ (qr & 7);
                    PsW[qr * 64 + slot * 8 + (l16 & 7)] = bf16_rn(pp);
                }
                l_run[r] += lsum;
            }
        }

        // ---- PV: O[16 q][64 d] += P @ V (Ps wave-private; no barrier) ----
#pragma unroll
        for (int dt = 0; dt < 4; ++dt)
#pragma unroll
            for (int ks = 0; ks < 2; ++ks) {
                short8 ap = *(const short8*)&PsW[l16 * 64 + ((ks * 4 + quad) ^ ksl) * 8];
                short8 bv = *(const short8*)&VtC[(dt * 16 + l16) * 64 +
                                                 ((ks * 4 + quad) ^ ksl) * 8];
                o_acc[dt] = __builtin_amdgcn_mfma_f32_16x16x32_bf16(ap, bv, o_acc[dt], 0, 0, 0);
            }

        // one barrier/tile: drains prefetch + guards buffer reuse
        __syncthreads();
    }

    // ---- epilogue: reduce l across the 16 key-lanes, normalize, store ----
#pragma unroll
    for (int r = 0; r < 4; ++r) {
        float l = l_run[r];
#pragma unroll
        for (int off = 1; off < 16; off <<= 1)
            l += __shfl_xor(l, off);
        float inv = 1.f / l;
        int row = q0 + w * 16 + quad * 4 + r;
        float* optr = out + (size_t)(b * SEQ + row) * CDIM + h * HDIM;
#pragma unroll
        for (int dt = 0; dt < 4; ++dt)
            optr[dt * 16 + l16] = o_acc[dt][r] * inv;
    }
}

// ------------------------------- launch --------------------------------------
extern "C" void kernel_launch(void* const* d_in, const int* in_sizes, int n_in,
                              void* d_out, int out_size, void* d_ws, size_t ws_size,
                              hipStream_t stream) {
    const float* x      = (const float*)d_in[0];   // [B,T,C] fp32
    const float* w_attn = (const float*)d_in[1];   // [C,3C]  fp32
    const float* b_attn = (const float*)d_in[2];   // [3C]    fp32
    float* out = (float*)d_out;                    // [B,T,C] fp32

    // workspace: qk [4096][2048] 16.78MB | vT [1024][4096] 8.39MB | xb 8.39MB | wT 6.29MB
    short* qk  = (short*)d_ws;
    short* vT  = (short*)((char*)d_ws + 16777216);
    short* xb  = (short*)((char*)d_ws + 25165824);
    short* wT  = (short*)((char*)d_ws + 33554432);

    cvt_fused<<<2048 + 768, 256, 0, stream>>>(x, w_attn, xb, wT);

    dim3 g1(N_GEMM / 128, M_GEMM / 128);                                // (24,32)
    qkv_gemm_mfma<<<g1, 256, 0, stream>>>(xb, wT, b_attn, qk, vT);

    dim3 g2(SEQ / 64, NHEAD, BSZ);                                      // (32,16,2)
    attn_mfma<<<g2, 256, 0, stream>>>(qk, vT, out);
}